// Round 1
// baseline (114.216 us; speedup 1.0000x reference)
//
#include <hip/hip_runtime.h>

// TurnUtteranceVadCrossEntropyLoss
//   y:     (T=4096, B=512, 7) fp32
//   t:     (T, B, 3) int32 (JAX x64 off -> int64 canonicalizes to int32)
//   y_len: (B,) int32
// out: scalar fp32 = (1/B) * sum_b [ (1/len_b) * sum_{tt<len_b} (ce3 + ce2 + ce2) ]

#define TT 4096
#define BB 512

__global__ __launch_bounds__(256) void ce_loss_kernel(
    const float* __restrict__ y,
    const int* __restrict__ t,
    const int* __restrict__ y_len,
    float* __restrict__ out)
{
    const int gid    = blockIdx.x * blockDim.x + threadIdx.x;
    const int b      = gid & (BB - 1);          // loop-invariant column
    const int tt0    = gid >> 9;                // starting row (0..511)
    const int tstride = (gridDim.x * blockDim.x) >> 9; // rows per step (512)

    int len = y_len[b];
    if (len > TT) len = TT;
    const float w = (len > 0) ? 1.0f / ((float)len * (float)BB) : 0.0f;

    float acc = 0.0f;
    for (int tt = tt0; tt < len; tt += tstride) {
        const long long idx = (long long)tt * BB + b;
        const float* yp = y + idx * 7;
        float l0 = yp[0], l1 = yp[1], l2 = yp[2];
        float l3 = yp[3], l4 = yp[4];
        float l5 = yp[5], l6 = yp[6];
        const int* tp = t + idx * 3;
        int t0 = tp[0], t1 = tp[1], t2 = tp[2];

        // 3-class head: nll = logsumexp(l0,l1,l2) - l_target
        float m  = fmaxf(l0, fmaxf(l1, l2));
        float se = __expf(l0 - m) + __expf(l1 - m) + __expf(l2 - m);
        float lt = (t0 == 0) ? l0 : ((t0 == 1) ? l1 : l2);
        float nll = m + __logf(se) - lt;

        // 2-class heads: nll = softplus(l_other - l_target)
        {
            float a = (t1 == 0) ? l3 : l4;
            float o = (t1 == 0) ? l4 : l3;
            float x = o - a;
            nll += fmaxf(x, 0.0f) + __logf(1.0f + __expf(-fabsf(x)));
        }
        {
            float a = (t2 == 0) ? l5 : l6;
            float o = (t2 == 0) ? l6 : l5;
            float x = o - a;
            nll += fmaxf(x, 0.0f) + __logf(1.0f + __expf(-fabsf(x)));
        }

        acc += nll * w;
    }

    // wave (64-lane) shuffle reduce
    #pragma unroll
    for (int off = 32; off > 0; off >>= 1)
        acc += __shfl_down(acc, off, 64);

    __shared__ float s_red[4]; // 256 threads / 64 lanes = 4 waves
    const int wave = threadIdx.x >> 6;
    const int lane = threadIdx.x & 63;
    if (lane == 0) s_red[wave] = acc;
    __syncthreads();
    if (threadIdx.x == 0) {
        float s = s_red[0] + s_red[1] + s_red[2] + s_red[3];
        atomicAdd(out, s);
    }
}

extern "C" void kernel_launch(void* const* d_in, const int* in_sizes, int n_in,
                              void* d_out, int out_size, void* d_ws, size_t ws_size,
                              hipStream_t stream) {
    const float* y     = (const float*)d_in[0];
    const int*   t     = (const int*)d_in[1];
    const int*   y_len = (const int*)d_in[2];
    float*       out   = (float*)d_out;

    // d_out is poisoned to 0xAA before each timed launch — zero it (capture-safe).
    hipMemsetAsync(out, 0, sizeof(float), stream);

    // grid*block = 1024*256 = 2^18 threads; stride over tt = 2^18/512 = 512 rows,
    // so each thread owns one column b and y_len[b]/w hoist out of the loop.
    ce_loss_kernel<<<dim3(1024), dim3(256), 0, stream>>>(y, t, y_len, out);
}

// Round 2
// 105.800 us; speedup vs baseline: 1.0796x; 1.0796x over previous
//
#include <hip/hip_runtime.h>

// TurnUtteranceVadCrossEntropyLoss
//   y:     (T=4096, B=512, 7) fp32
//   t:     (T, B, 3) int32
//   y_len: (B,) int32
// out: scalar fp32 = (1/B) * sum_b [ (1/len_b) * sum_{tt<len_b} (ce3 + ce2 + ce2) ]
//
// R1 restructure:
//  - fixed 4-row chunk per thread, load phase (all rows) separated from compute
//    phase to keep ~40 loads in flight per wave (latency hiding)
//  - 2048 blocks -> 8 waves/SIMD occupancy (VGPR permitting)
//  - no same-address atomics: per-block partials in d_ws + second reduce kernel

#define T_DIM 4096
#define B_DIM 512
#define RPT   4                      // rows per thread
#define NCHUNK (T_DIM / RPT)         // 1024 chunks
#define NTHREADS (B_DIM * NCHUNK)    // 524288
#define NBLOCKS (NTHREADS / 256)     // 2048

struct Y7 { float f[7]; };
struct T3 { int   i[3]; };

__global__ __launch_bounds__(256) void ce_partial_kernel(
    const float* __restrict__ y,
    const int* __restrict__ t,
    const int* __restrict__ y_len,
    float* __restrict__ partial)
{
    const int gid   = blockIdx.x * 256 + threadIdx.x;
    const int b     = gid & (B_DIM - 1);   // consecutive lanes -> consecutive b (coalesced)
    const int chunk = gid >> 9;            // 0..NCHUNK-1
    const int r0    = chunk * RPT;

    int len = y_len[b];
    len = (len < 0) ? 0 : ((len > T_DIM) ? T_DIM : len);
    const float w = (len > 0) ? 1.0f / ((float)len * (float)B_DIM) : 0.0f;

    int kv = len - r0;                     // valid rows in this chunk
    kv = (kv < 0) ? 0 : ((kv > RPT) ? RPT : kv);

    // ---- load phase: issue all rows' loads before any compute ----
    float ly[RPT][7];
    int   lt[RPT][3];
    #pragma unroll
    for (int j = 0; j < RPT; ++j) {
        if (j < kv) {
            const size_t idx = (size_t)(r0 + j) * B_DIM + b;
            Y7 yv = *(const Y7*)(y + idx * 7);   // dwordx4 + dwordx3
            T3 tv = *(const T3*)(t + idx * 3);   // dwordx3
            #pragma unroll
            for (int k = 0; k < 7; ++k) ly[j][k] = yv.f[k];
            #pragma unroll
            for (int k = 0; k < 3; ++k) lt[j][k] = tv.i[k];
        }
    }

    // ---- compute phase ----
    float acc = 0.0f;
    #pragma unroll
    for (int j = 0; j < RPT; ++j) {
        if (j < kv) {
            float l0 = ly[j][0], l1 = ly[j][1], l2 = ly[j][2];
            float l3 = ly[j][3], l4 = ly[j][4];
            float l5 = ly[j][5], l6 = ly[j][6];
            int t0 = lt[j][0], t1 = lt[j][1], t2 = lt[j][2];

            // 3-class head
            float m  = fmaxf(l0, fmaxf(l1, l2));
            float se = __expf(l0 - m) + __expf(l1 - m) + __expf(l2 - m);
            float tgt = (t0 == 0) ? l0 : ((t0 == 1) ? l1 : l2);
            float nll = m + __logf(se) - tgt;

            // 2-class heads: softplus(l_other - l_target)
            {
                float a = (t1 == 0) ? l3 : l4;
                float o = (t1 == 0) ? l4 : l3;
                float x = o - a;
                nll += fmaxf(x, 0.0f) + __logf(1.0f + __expf(-fabsf(x)));
            }
            {
                float a = (t2 == 0) ? l5 : l6;
                float o = (t2 == 0) ? l6 : l5;
                float x = o - a;
                nll += fmaxf(x, 0.0f) + __logf(1.0f + __expf(-fabsf(x)));
            }
            acc += nll;
        }
    }
    acc *= w;

    // ---- block reduce -> one partial per block ----
    #pragma unroll
    for (int off = 32; off > 0; off >>= 1)
        acc += __shfl_down(acc, off, 64);

    __shared__ float s_red[4];
    const int wave = threadIdx.x >> 6;
    const int lane = threadIdx.x & 63;
    if (lane == 0) s_red[wave] = acc;
    __syncthreads();
    if (threadIdx.x == 0)
        partial[blockIdx.x] = s_red[0] + s_red[1] + s_red[2] + s_red[3];
}

__global__ __launch_bounds__(256) void ce_reduce_kernel(
    const float* __restrict__ partial, float* __restrict__ out)
{
    float a = 0.0f;
    for (int i = threadIdx.x; i < NBLOCKS; i += 256)
        a += partial[i];

    #pragma unroll
    for (int off = 32; off > 0; off >>= 1)
        a += __shfl_down(a, off, 64);

    __shared__ float s_red[4];
    const int wave = threadIdx.x >> 6;
    const int lane = threadIdx.x & 63;
    if (lane == 0) s_red[wave] = a;
    __syncthreads();
    if (threadIdx.x == 0)
        out[0] = s_red[0] + s_red[1] + s_red[2] + s_red[3];
}

extern "C" void kernel_launch(void* const* d_in, const int* in_sizes, int n_in,
                              void* d_out, int out_size, void* d_ws, size_t ws_size,
                              hipStream_t stream) {
    const float* y     = (const float*)d_in[0];
    const int*   t     = (const int*)d_in[1];
    const int*   y_len = (const int*)d_in[2];
    float*       out   = (float*)d_out;
    float*       partial = (float*)d_ws;   // NBLOCKS floats = 8 KB

    // every partial slot is written unconditionally by kernel 1, and
    // ce_reduce_kernel overwrites out[0] -> no memset needed (poison-safe).
    ce_partial_kernel<<<dim3(NBLOCKS), dim3(256), 0, stream>>>(y, t, y_len, partial);
    ce_reduce_kernel<<<dim3(1), dim3(256), 0, stream>>>(partial, out);
}

// Round 3
// 105.736 us; speedup vs baseline: 1.0802x; 1.0006x over previous
//
#include <hip/hip_runtime.h>

// TurnUtteranceVadCrossEntropyLoss
//   y:     (T=4096, B=512, 7) fp32
//   t:     (T, B, 3) int32
//   y_len: (B,) int32
// out: scalar fp32 = (1/B) * sum_b [ (1/len_b) * sum_{tt<len_b} (ce3 + ce2 + ce2) ]
//
// R2: RPT=8 (24 loads in flight/thread), 1024 blocks, __launch_bounds__(256,4)
// for a 128-VGPR budget (8 rows x 10 live regs in the load phase).
// Kernel-side HBM floor ~11 us (69 MB effective fetch at line granularity);
// harness poison/restore (~80 us) dominates total dur_us.

#define T_DIM 4096
#define B_DIM 512
#define RPT   8                      // rows per thread
#define NCHUNK (T_DIM / RPT)         // 512 chunks
#define NTHREADS (B_DIM * NCHUNK)    // 262144
#define NBLOCKS (NTHREADS / 256)     // 1024

struct Y7 { float f[7]; };
struct T3 { int   i[3]; };

__global__ __launch_bounds__(256, 4) void ce_partial_kernel(
    const float* __restrict__ y,
    const int* __restrict__ t,
    const int* __restrict__ y_len,
    float* __restrict__ partial)
{
    const int gid   = blockIdx.x * 256 + threadIdx.x;
    const int b     = gid & (B_DIM - 1);   // consecutive lanes -> consecutive b (coalesced)
    const int chunk = gid >> 9;            // 0..NCHUNK-1
    const int r0    = chunk * RPT;

    int len = y_len[b];
    len = (len < 0) ? 0 : ((len > T_DIM) ? T_DIM : len);
    const float w = (len > 0) ? 1.0f / ((float)len * (float)B_DIM) : 0.0f;

    int kv = len - r0;                     // valid rows in this chunk
    kv = (kv < 0) ? 0 : ((kv > RPT) ? RPT : kv);

    // ---- load phase: issue all rows' loads before any compute ----
    float ly[RPT][7];
    int   lt[RPT][3];
    const size_t base = (size_t)r0 * B_DIM + b;
    #pragma unroll
    for (int j = 0; j < RPT; ++j) {
        if (j < kv) {
            const size_t idx = base + (size_t)j * B_DIM;
            Y7 yv = *(const Y7*)(y + idx * 7);   // dwordx4 + dwordx3
            T3 tv = *(const T3*)(t + idx * 3);   // dwordx3
            #pragma unroll
            for (int k = 0; k < 7; ++k) ly[j][k] = yv.f[k];
            #pragma unroll
            for (int k = 0; k < 3; ++k) lt[j][k] = tv.i[k];
        }
    }

    // ---- compute phase ----
    float acc = 0.0f;
    #pragma unroll
    for (int j = 0; j < RPT; ++j) {
        if (j < kv) {
            float l0 = ly[j][0], l1 = ly[j][1], l2 = ly[j][2];
            float l3 = ly[j][3], l4 = ly[j][4];
            float l5 = ly[j][5], l6 = ly[j][6];
            int t0 = lt[j][0], t1 = lt[j][1], t2 = lt[j][2];

            // 3-class head
            float m  = fmaxf(l0, fmaxf(l1, l2));
            float se = __expf(l0 - m) + __expf(l1 - m) + __expf(l2 - m);
            float tgt = (t0 == 0) ? l0 : ((t0 == 1) ? l1 : l2);
            float nll = m + __logf(se) - tgt;

            // 2-class heads: softplus(l_other - l_target)
            {
                float a = (t1 == 0) ? l3 : l4;
                float o = (t1 == 0) ? l4 : l3;
                float x = o - a;
                nll += fmaxf(x, 0.0f) + __logf(1.0f + __expf(-fabsf(x)));
            }
            {
                float a = (t2 == 0) ? l5 : l6;
                float o = (t2 == 0) ? l6 : l5;
                float x = o - a;
                nll += fmaxf(x, 0.0f) + __logf(1.0f + __expf(-fabsf(x)));
            }
            acc += nll;
        }
    }
    acc *= w;

    // ---- block reduce -> one partial per block ----
    #pragma unroll
    for (int off = 32; off > 0; off >>= 1)
        acc += __shfl_down(acc, off, 64);

    __shared__ float s_red[4];
    const int wave = threadIdx.x >> 6;
    const int lane = threadIdx.x & 63;
    if (lane == 0) s_red[wave] = acc;
    __syncthreads();
    if (threadIdx.x == 0)
        partial[blockIdx.x] = s_red[0] + s_red[1] + s_red[2] + s_red[3];
}

__global__ __launch_bounds__(256) void ce_reduce_kernel(
    const float* __restrict__ partial, float* __restrict__ out)
{
    float a = 0.0f;
    #pragma unroll
    for (int i = 0; i < NBLOCKS / 256; ++i)
        a += partial[i * 256 + threadIdx.x];

    #pragma unroll
    for (int off = 32; off > 0; off >>= 1)
        a += __shfl_down(a, off, 64);

    __shared__ float s_red[4];
    const int wave = threadIdx.x >> 6;
    const int lane = threadIdx.x & 63;
    if (lane == 0) s_red[wave] = a;
    __syncthreads();
    if (threadIdx.x == 0)
        out[0] = s_red[0] + s_red[1] + s_red[2] + s_red[3];
}

extern "C" void kernel_launch(void* const* d_in, const int* in_sizes, int n_in,
                              void* d_out, int out_size, void* d_ws, size_t ws_size,
                              hipStream_t stream) {
    const float* y     = (const float*)d_in[0];
    const int*   t     = (const int*)d_in[1];
    const int*   y_len = (const int*)d_in[2];
    float*       out   = (float*)d_out;
    float*       partial = (float*)d_ws;   // NBLOCKS floats = 4 KB

    // every partial slot is written unconditionally by kernel 1, and
    // ce_reduce_kernel overwrites out[0] -> no memset needed (poison-safe).
    ce_partial_kernel<<<dim3(NBLOCKS), dim3(256), 0, stream>>>(y, t, y_len, partial);
    ce_reduce_kernel<<<dim3(1), dim3(256), 0, stream>>>(partial, out);
}